// Round 2
// baseline (26251.755 us; speedup 1.0000x reference)
//
#include <hip/hip_runtime.h>

typedef _Float16 h2f __attribute__((ext_vector_type(2)));

#define LOG2E 1.44269504088896f

__device__ __forceinline__ float fexp2(float x){ return __builtin_amdgcn_exp2f(x); }
__device__ __forceinline__ float frcp (float x){ return __builtin_amdgcn_rcpf(x); }
__device__ __forceinline__ float sigm (float x){ return frcp(1.f + fexp2(-LOG2E*x)); }
__device__ __forceinline__ float tanhf2(float x){
  x = fminf(15.f, fmaxf(-15.f, x));
  float e = fexp2(2.f*LOG2E*x);
  return (e-1.f)*frcp(e+1.f);
}
__device__ __forceinline__ unsigned pkh2(float a, float b){
  h2f h; h.x = (_Float16)a; h.y = (_Float16)b;
  return __builtin_bit_cast(unsigned, h);
}

#if __has_builtin(__builtin_amdgcn_fdot2)
__device__ __forceinline__ float dot2(unsigned a, unsigned b, float c){
  return __builtin_amdgcn_fdot2(__builtin_bit_cast(h2f,a), __builtin_bit_cast(h2f,b), c, false);
}
#else
__device__ __forceinline__ float dot2(unsigned a, unsigned b, float c){
  h2f ha=__builtin_bit_cast(h2f,a), hb=__builtin_bit_cast(h2f,b);
  return c + (float)ha.x*(float)hb.x + (float)ha.y*(float)hb.y;
}
#endif

__device__ __forceinline__ void dot8_2(uint4 w, uint4 x, float& a0, float& a1){
  a0 = dot2(w.x, x.x, a0); a1 = dot2(w.y, x.y, a1);
  a0 = dot2(w.z, x.z, a0); a1 = dot2(w.w, x.w, a1);
}

// out[n] = sum_k W[n,k]*x[k]; W packed [k8][N] uint4 (8 halves of row n), x packed LDS half2
template<int N, int K8>
__device__ __forceinline__ float mv(const uint4* __restrict__ W, const uint4* __restrict__ xs, int n){
  float a0 = 0.f, a1 = 0.f;
  #pragma unroll 4
  for (int k8 = 0; k8 < K8; ++k8)
    dot8_2(W[k8*N + n], xs[k8], a0, a1);
  return a0 + a1;
}

// ---------------- workspace layout (bytes) ----------------
static constexpr size_t OFF_W1   = 0;          // 256x400 -> 204800
static constexpr size_t OFF_W2   = 204800;     // 128x256 -> 65536
static constexpr size_t OFF_WIHA = 270336;     // 768x384 -> 589824
static constexpr size_t OFF_WHHA = 860160;     // 768x256 -> 393216
static constexpr size_t OFF_WQ   = 1253376;    // 256x256 -> 131072
static constexpr size_t OFF_WP   = 1384448;    // 256x512 -> 262144
static constexpr size_t OFF_WD1I = 1646592;    // 768x256
static constexpr size_t OFF_WD1H = 2039808;
static constexpr size_t OFF_WD2I = 2433024;
static constexpr size_t OFF_WD2H = 2826240;
static constexpr size_t OFF_WMEL = 3219456;    // 400x256 -> 204800
static constexpr size_t OFF_WM   = 3424256;    // 256x256 -> 131072
static constexpr size_t OFF_TPM  = 3555328;    // tanh(pm) f16 [128][128][512] -> 33554432
static constexpr size_t OFF_ENCH = 37109760;   // enc f16 [128][512][128] -> 33554432
// total ~70.7 MB

// ---------------- prep kernels ----------------
__global__ void pack_w(const float* __restrict__ src, uint4* __restrict__ dst, int N, int K8){
  int idx = blockIdx.x*blockDim.x + threadIdx.x;
  if (idx >= N*K8) return;
  int n = idx % N, k8 = idx / N;
  const float* s = src + (size_t)n*(K8*8) + k8*8;
  dst[idx] = make_uint4(pkh2(s[0],s[1]), pkh2(s[2],s[3]), pkh2(s[4],s[5]), pkh2(s[6],s[7]));
}

__global__ void conv_enc(const float* __restrict__ enc, unsigned* __restrict__ encH){
  size_t i = blockIdx.x*(size_t)blockDim.x + threadIdx.x;   // over 128*512*128 half2
  if (i >= (size_t)128*512*128) return;
  const float2 f = *(const float2*)(enc + 2*i);
  encH[i] = pkh2(f.x, f.y);
}

// tanh(processed_mem) stored transposed: tpm[b][d2][t] (half2 of d-pair)
__global__ __launch_bounds__(1024) void pm_kernel(const float* __restrict__ enc,
    const uint4* __restrict__ Wmp, unsigned* __restrict__ tpm)
{
  int b = blockIdx.y, tc = blockIdx.x;   // 128 t-chunks of 4, 128 b
  int tid = threadIdx.x;
  __shared__ __align__(16) unsigned s_e[4][128];
  if (tid < 512){
    int r = tid >> 7, d2 = tid & 127;
    const float2 f = *(const float2*)(enc + ((size_t)b*512 + tc*4 + r)*256 + 2*d2);
    s_e[r][d2] = pkh2(f.x, f.y);
  }
  __syncthreads();
  int d = tid & 255, r = tid >> 8;
  float acc = mv<256,32>(Wmp, (const uint4*)s_e[r], d);
  float tq = tanhf2(acc);
  float hi = __shfl_down(tq, 1);
  if ((d & 1) == 0)
    tpm[(size_t)b*65536 + (size_t)(d>>1)*512 + (tc*4 + r)] = pkh2(tq, hi);
}

// ---------------- decoder ----------------
__device__ __forceinline__ void gru_phase(
    const uint4* __restrict__ Wi, const uint4* __restrict__ Wh,
    const float* __restrict__ bih, const float* __restrict__ bhh,
    const unsigned* __restrict__ xs2, const unsigned* __restrict__ hs2,
    float* hF, unsigned* hP, float* s_g, int tid, int K8X, int K8H)
{
  float gi = 0.f, gh = 0.f;
  if (tid < 768){
    if (K8X == 48) gi = mv<768,48>(Wi, (const uint4*)xs2, tid);
    else           gi = mv<768,32>(Wi, (const uint4*)xs2, tid);
    gi += bih[tid];
    gh = mv<768,32>(Wh, (const uint4*)hs2, tid) + bhh[tid];
  }
  if (tid < 512) s_g[tid] = sigm(gi + gh);
  else if (tid < 768){ s_g[tid] = gi; s_g[tid + 256] = gh; }
  __syncthreads();
  if (tid < 256){
    float r = s_g[tid], z = s_g[256+tid];
    float nv = tanhf2(s_g[512+tid] + r*s_g[768+tid]);
    float h  = nv + z*(hF[tid] - nv);     // (1-z)*n + z*h
    hF[tid] = h;
    s_g[tid] = h;                          // for packing
  }
  __syncthreads();
  if (tid < 128) hP[tid] = pkh2(s_g[2*tid], s_g[2*tid+1]);
  // caller syncs
}

__global__ __launch_bounds__(1024) void decoder(
   const float* __restrict__ inputs,
   const float* __restrict__ b1, const float* __restrict__ b2,
   const float* __restrict__ biha, const float* __restrict__ bhha,
   const float* __restrict__ vvec, const float* __restrict__ bp,
   const float* __restrict__ bd1i, const float* __restrict__ bd1h,
   const float* __restrict__ bd2i, const float* __restrict__ bd2h,
   const float* __restrict__ bmel,
   const uint4* __restrict__ W1p, const uint4* __restrict__ W2p,
   const uint4* __restrict__ Wihap, const uint4* __restrict__ Whhap,
   const uint4* __restrict__ Wqp, const uint4* __restrict__ Wpp,
   const uint4* __restrict__ Wd1ip, const uint4* __restrict__ Wd1hp,
   const uint4* __restrict__ Wd2ip, const uint4* __restrict__ Wd2hp,
   const uint4* __restrict__ Wmelp,
   const unsigned* __restrict__ tpm, const unsigned* __restrict__ encH,
   float* __restrict__ out)
{
  const int tid = threadIdx.x;
  const int b = blockIdx.x;

  __shared__ __align__(16) unsigned s_x2[200];   // prenet input (400 halves)
  __shared__ __align__(16) unsigned s_p1[128];   // prenet hidden1 (256)
  __shared__ __align__(16) unsigned s_cin2[192]; // [pre(128) | ctx(256)]
  __shared__ __align__(16) unsigned s_cat2[256]; // [attn_h(256) | ctx(256)]
  __shared__ __align__(16) unsigned s_di2[128];  // dec_in (256)
  __shared__ __align__(16) unsigned s_h12[128];
  __shared__ __align__(16) unsigned s_h22[128];
  __shared__ float  s_g[1024];      // gate scratch: r/z [0..511], gi_n [512..767], gh_n [768..1023]
  __shared__ float  s_ahf[256];     // attn_h fp32
  __shared__ float  s_h1f[256], s_h2f[256];
  __shared__ float  s_dif[256];     // dec_in fp32 (residual chain)
  __shared__ float4 s_tv[128];      // {tanh(q)[2d2], tanh(q)[2d2+1], v[2d2], v[2d2+1]}
  __shared__ float  s_lp[2][512];   // logit partials
  __shared__ float2 s_cp[8][128];   // ctx partials
  __shared__ float  s_mvp[4][256];  // split-K partials
  __shared__ float  s_align[512];
  __shared__ float  s_red[32];

  // init (all recurrent state zero)
  if (tid < 200) s_x2[tid] = 0u;
  if (tid < 192) s_cin2[tid] = 0u;
  if (tid < 256){ s_cat2[tid]=0u; s_ahf[tid]=0.f; s_h1f[tid]=0.f; s_h2f[tid]=0.f; }
  if (tid < 128){ s_h12[tid]=0u; s_h22[tid]=0u;
                  s_tv[tid].z = vvec[2*tid]; s_tv[tid].w = vvec[2*tid+1]; }
  __syncthreads();

  const unsigned* tpmB = tpm  + (size_t)b*65536;
  const unsigned* encB = encH + (size_t)b*65536;
  const float*    inB  = inputs + (size_t)b*80000;
  float* outMel = out + (size_t)b*200*400;
  float* outAl  = out + (size_t)10240000 + (size_t)b*200*512;

  for (int t = 0; t < 200; ++t){
    // ---- phase 1: x_t = frame t-1 (zeros at t=0), pack to f16x2
    if (tid < 200){
      unsigned xv = 0u;
      if (t > 0){
        const float2 f = *(const float2*)(inB + (size_t)(t-1)*400 + 2*tid);
        xv = pkh2(f.x, f.y);
      }
      s_x2[tid] = xv;
    }
    __syncthreads();
    // ---- phase 2: prenet1 (256 <- 400), relu
    if (tid < 256){
      float a = mv<256,50>(W1p, (const uint4*)s_x2, tid) + b1[tid];
      s_g[tid] = fmaxf(a, 0.f);
    }
    __syncthreads();
    if (tid < 128) s_p1[tid] = pkh2(s_g[2*tid], s_g[2*tid+1]);
    __syncthreads();
    // ---- phase 3: prenet2 (128 <- 256), relu -> cell_in[0:128]
    if (tid < 128){
      float a = mv<128,32>(W2p, (const uint4*)s_p1, tid) + b2[tid];
      s_g[256+tid] = fmaxf(a, 0.f);
    }
    __syncthreads();
    if (tid < 64) s_cin2[tid] = pkh2(s_g[256+2*tid], s_g[256+2*tid+1]);
    __syncthreads();
    // ---- phase 4: attention GRU (in: cell_in 384, h: attn_h 256)
    gru_phase(Wihap, Whhap, biha, bhha, s_cin2, s_cat2, s_ahf, s_cat2, s_g, tid, 48, 32);
    __syncthreads();
    // ---- phase 5: q = attn_h @ Wq.T (split-K4), then tanh(q)
    {
      int n = tid & 255, p = tid >> 8;
      float a0 = 0.f, a1 = 0.f;
      #pragma unroll
      for (int k8 = 0; k8 < 8; ++k8)
        dot8_2(Wqp[(8*p+k8)*256 + n], ((const uint4*)s_cat2)[8*p+k8], a0, a1);
      s_mvp[p][n] = a0 + a1;
    }
    __syncthreads();
    if (tid < 256){
      float q = s_mvp[0][tid]+s_mvp[1][tid]+s_mvp[2][tid]+s_mvp[3][tid];
      ((float*)&s_tv[tid>>1])[tid&1] = tanhf2(q);
    }
    __syncthreads();
    // ---- phase 6: logits[t'] = sum_d v_d * tanh(q_d + pm[t',d]) via tanh-sum identity
    {
      int tt = tid & 511, dh = tid >> 9;
      float acc = 0.f;
      const unsigned* tp = tpmB + tt;
      #pragma unroll 4
      for (int j = 0; j < 64; ++j){
        int d2 = dh*64 + j;
        h2f ta = __builtin_bit_cast(h2f, tp[(size_t)d2*512]);
        float4 tv = s_tv[d2];
        float ta0 = (float)ta.x, ta1 = (float)ta.y;
        float u0 = (ta0+tv.x)*frcp(1.f+ta0*tv.x);
        float u1 = (ta1+tv.y)*frcp(1.f+ta1*tv.y);
        acc += tv.z*u0 + tv.w*u1;
      }
      s_lp[dh][tt] = acc;
    }
    __syncthreads();
    // ---- softmax over 512
    {
      float lg = (tid < 512) ? (s_lp[0][tid] + s_lp[1][tid]) : -1e30f;
      float m = lg;
      #pragma unroll
      for (int off = 32; off >= 1; off >>= 1) m = fmaxf(m, __shfl_xor(m, off));
      if ((tid & 63) == 0) s_red[tid>>6] = m;
      __syncthreads();
      float M = fmaxf(fmaxf(fmaxf(s_red[0],s_red[1]),fmaxf(s_red[2],s_red[3])),
                      fmaxf(fmaxf(s_red[4],s_red[5]),fmaxf(s_red[6],s_red[7])));
      float e = (tid < 512) ? fexp2(LOG2E*(lg - M)) : 0.f;
      float s = e;
      #pragma unroll
      for (int off = 32; off >= 1; off >>= 1) s += __shfl_xor(s, off);
      if ((tid & 63) == 0) s_red[16+(tid>>6)] = s;
      __syncthreads();
      float S = (s_red[16]+s_red[17])+(s_red[18]+s_red[19])
              + (s_red[20]+s_red[21])+(s_red[22]+s_red[23]);
      float a = e * frcp(S);
      if (tid < 512){ s_align[tid] = a; outAl[(size_t)t*512 + tid] = a; }
    }
    __syncthreads();
    // ---- phase 7: ctx[d] = sum_t align[t]*enc[t,d]
    {
      int d2 = tid & 127, tc = tid >> 7;
      float ax = 0.f, ay = 0.f;
      const unsigned* eb = encB + d2;
      #pragma unroll 4
      for (int j = 0; j < 64; ++j){
        int tt2 = tc*64 + j;
        float a = s_align[tt2];
        h2f e2 = __builtin_bit_cast(h2f, eb[(size_t)tt2*128]);
        ax += a*(float)e2.x; ay += a*(float)e2.y;
      }
      s_cp[tc][d2] = make_float2(ax, ay);
    }
    __syncthreads();
    if (tid < 256){
      const float* cp = (const float*)s_cp;   // [tc][d2][2] -> flat tc*256 + d
      float c = 0.f;
      #pragma unroll
      for (int tc = 0; tc < 8; ++tc) c += cp[tc*256 + tid];
      s_g[tid] = c;
    }
    __syncthreads();
    if (tid < 128){
      unsigned pk = pkh2(s_g[2*tid], s_g[2*tid+1]);
      s_cin2[64+tid] = pk;    // ctx for next step's cell_in
      s_cat2[128+tid] = pk;   // ctx for dec projection
    }
    __syncthreads();
    // ---- phase 8: dec_in = cat(attn_h, ctx) @ Wp.T + bp (split-K4, K=512)
    {
      int n = tid & 255, p = tid >> 8;
      float a0 = 0.f, a1 = 0.f;
      #pragma unroll 4
      for (int k8 = 0; k8 < 16; ++k8)
        dot8_2(Wpp[(16*p+k8)*256 + n], ((const uint4*)s_cat2)[16*p+k8], a0, a1);
      s_mvp[p][n] = a0 + a1;
    }
    __syncthreads();
    if (tid < 256) s_dif[tid] = s_mvp[0][tid]+s_mvp[1][tid]+s_mvp[2][tid]+s_mvp[3][tid] + bp[tid];
    __syncthreads();
    if (tid < 128) s_di2[tid] = pkh2(s_dif[2*tid], s_dif[2*tid+1]);
    __syncthreads();
    // ---- phase 9: decoder GRU 1 + residual
    gru_phase(Wd1ip, Wd1hp, bd1i, bd1h, s_di2, s_h12, s_h1f, s_h12, s_g, tid, 32, 32);
    __syncthreads();
    if (tid < 256) s_dif[tid] += s_h1f[tid];
    __syncthreads();
    if (tid < 128) s_di2[tid] = pkh2(s_dif[2*tid], s_dif[2*tid+1]);
    __syncthreads();
    // ---- phase 10: decoder GRU 2 + residual
    gru_phase(Wd2ip, Wd2hp, bd2i, bd2h, s_di2, s_h22, s_h2f, s_h22, s_g, tid, 32, 32);
    __syncthreads();
    if (tid < 256) s_dif[tid] += s_h2f[tid];
    __syncthreads();
    if (tid < 128) s_di2[tid] = pkh2(s_dif[2*tid], s_dif[2*tid+1]);
    __syncthreads();
    // ---- phase 11: mel = dec_in @ Wmel.T + bmel
    if (tid < 400){
      float a = mv<400,32>(Wmelp, (const uint4*)s_di2, tid) + bmel[tid];
      outMel[(size_t)t*400 + tid] = a;
    }
    __syncthreads();
  }
}

// ---------------- launch ----------------
extern "C" void kernel_launch(void* const* d_in, const int* in_sizes, int n_in,
                              void* d_out, int out_size, void* d_ws, size_t ws_size,
                              hipStream_t stream){
  (void)in_sizes; (void)n_in; (void)out_size; (void)ws_size;
  const float* enc    = (const float*)d_in[0];
  const float* inputs = (const float*)d_in[1];
  const float* W1 = (const float*)d_in[2];   const float* b1 = (const float*)d_in[3];
  const float* W2 = (const float*)d_in[4];   const float* b2 = (const float*)d_in[5];
  const float* Wiha = (const float*)d_in[6]; const float* Whha = (const float*)d_in[7];
  const float* biha = (const float*)d_in[8]; const float* bhha = (const float*)d_in[9];
  const float* Wq = (const float*)d_in[10];  const float* v  = (const float*)d_in[11];
  const float* Wm = (const float*)d_in[12];
  const float* Wp = (const float*)d_in[13];  const float* bp = (const float*)d_in[14];
  const float* Wd1i = (const float*)d_in[15]; const float* Wd1h = (const float*)d_in[16];
  const float* bd1i = (const float*)d_in[17]; const float* bd1h = (const float*)d_in[18];
  const float* Wd2i = (const float*)d_in[19]; const float* Wd2h = (const float*)d_in[20];
  const float* bd2i = (const float*)d_in[21]; const float* bd2h = (const float*)d_in[22];
  const float* Wmel = (const float*)d_in[23]; const float* bmel = (const float*)d_in[24];

  char* ws = (char*)d_ws;
  uint4* W1p   = (uint4*)(ws + OFF_W1);
  uint4* W2p   = (uint4*)(ws + OFF_W2);
  uint4* Wihap = (uint4*)(ws + OFF_WIHA);
  uint4* Whhap = (uint4*)(ws + OFF_WHHA);
  uint4* Wqp   = (uint4*)(ws + OFF_WQ);
  uint4* Wpp   = (uint4*)(ws + OFF_WP);
  uint4* Wd1ip = (uint4*)(ws + OFF_WD1I);
  uint4* Wd1hp = (uint4*)(ws + OFF_WD1H);
  uint4* Wd2ip = (uint4*)(ws + OFF_WD2I);
  uint4* Wd2hp = (uint4*)(ws + OFF_WD2H);
  uint4* Wmelp = (uint4*)(ws + OFF_WMEL);
  uint4* Wmp   = (uint4*)(ws + OFF_WM);
  unsigned* tpm  = (unsigned*)(ws + OFF_TPM);
  unsigned* encH = (unsigned*)(ws + OFF_ENCH);

  auto P = [&](const float* s, uint4* dst, int N, int K){
    int k8 = K/8, tot = N*k8;
    pack_w<<<(tot+255)/256, 256, 0, stream>>>(s, dst, N, k8);
  };
  P(W1, W1p, 256, 400);   P(W2, W2p, 128, 256);
  P(Wiha, Wihap, 768, 384); P(Whha, Whhap, 768, 256);
  P(Wq, Wqp, 256, 256);   P(Wm, Wmp, 256, 256);
  P(Wp, Wpp, 256, 512);
  P(Wd1i, Wd1ip, 768, 256); P(Wd1h, Wd1hp, 768, 256);
  P(Wd2i, Wd2ip, 768, 256); P(Wd2h, Wd2hp, 768, 256);
  P(Wmel, Wmelp, 400, 256);

  conv_enc<<<32768, 256, 0, stream>>>(enc, encH);
  pm_kernel<<<dim3(128,128), 1024, 0, stream>>>(enc, Wmp, tpm);

  decoder<<<128, 1024, 0, stream>>>(inputs,
      b1, b2, biha, bhha, v, bp, bd1i, bd1h, bd2i, bd2h, bmel,
      W1p, W2p, Wihap, Whhap, Wqp, Wpp, Wd1ip, Wd1hp, Wd2ip, Wd2hp, Wmelp,
      tpm, encH, (float*)d_out);
}

// Round 3
// 9522.133 us; speedup vs baseline: 2.7569x; 2.7569x over previous
//
#include <hip/hip_runtime.h>

typedef _Float16 h2f __attribute__((ext_vector_type(2)));

#define LOG2E 1.44269504088896f

__device__ __forceinline__ float fexp2(float x){ return __builtin_amdgcn_exp2f(x); }
__device__ __forceinline__ float frcp (float x){ return __builtin_amdgcn_rcpf(x); }
__device__ __forceinline__ float sigm (float x){ return frcp(1.f + fexp2(-LOG2E*x)); }
__device__ __forceinline__ float tanhf2(float x){
  x = fminf(15.f, fmaxf(-15.f, x));
  float e = fexp2(2.f*LOG2E*x);
  return (e-1.f)*frcp(e+1.f);
}
__device__ __forceinline__ unsigned pkh2(float a, float b){
  h2f h; h.x = (_Float16)a; h.y = (_Float16)b;
  return __builtin_bit_cast(unsigned, h);
}

#if __has_builtin(__builtin_amdgcn_fdot2)
__device__ __forceinline__ float dot2(unsigned a, unsigned b, float c){
  return __builtin_amdgcn_fdot2(__builtin_bit_cast(h2f,a), __builtin_bit_cast(h2f,b), c, false);
}
#else
__device__ __forceinline__ float dot2(unsigned a, unsigned b, float c){
  h2f ha=__builtin_bit_cast(h2f,a), hb=__builtin_bit_cast(h2f,b);
  return c + (float)ha.x*(float)hb.x + (float)ha.y*(float)hb.y;
}
#endif

__device__ __forceinline__ void dot8_2(uint4 w, uint4 x, float& a0, float& a1){
  a0 = dot2(w.x, x.x, a0); a1 = dot2(w.y, x.y, a1);
  a0 = dot2(w.z, x.z, a0); a1 = dot2(w.w, x.w, a1);
}

// simple version (used by pm_kernel)
template<int N, int K8>
__device__ __forceinline__ float mv(const uint4* __restrict__ W, const uint4* __restrict__ xs, int n){
  float a0 = 0.f, a1 = 0.f;
  #pragma unroll 4
  for (int k8 = 0; k8 < K8; ++k8)
    dot8_2(W[k8*N + n], xs[k8], a0, a1);
  return a0 + a1;
}

// chunked load-then-compute: C uint4 loads issued back-to-back (deep MLP),
// then consumed. Keeps ~C loads in flight instead of ~4.
template<int N, int K8, int C>
__device__ __forceinline__ float mvc(const uint4* __restrict__ W, const uint4* __restrict__ xs, int n){
  float a0 = 0.f, a1 = 0.f;
  int k8 = 0;
  #pragma unroll 1
  for (; k8 + C <= K8; k8 += C){
    uint4 w[C];
    #pragma unroll
    for (int i = 0; i < C; ++i) w[i] = W[(size_t)(k8+i)*N + n];
    #pragma unroll
    for (int i = 0; i < C; ++i) dot8_2(w[i], xs[k8+i], a0, a1);
  }
  if constexpr (K8 % C){
    constexpr int R = K8 % C;
    uint4 w[R];
    #pragma unroll
    for (int i = 0; i < R; ++i) w[i] = W[(size_t)(k8+i)*N + n];
    #pragma unroll
    for (int i = 0; i < R; ++i) dot8_2(w[i], xs[k8+i], a0, a1);
  }
  return a0 + a1;
}

// ---------------- workspace layout (bytes) ----------------
static constexpr size_t OFF_W1   = 0;          // 256x400 -> 204800
static constexpr size_t OFF_W2   = 204800;     // 128x256 -> 65536
static constexpr size_t OFF_WIHA = 270336;     // 768x384 -> 589824
static constexpr size_t OFF_WHHA = 860160;     // 768x256 -> 393216
static constexpr size_t OFF_WQ   = 1253376;    // 256x256 -> 131072
static constexpr size_t OFF_WP   = 1384448;    // 256x512 -> 262144
static constexpr size_t OFF_WD1I = 1646592;    // 768x256
static constexpr size_t OFF_WD1H = 2039808;
static constexpr size_t OFF_WD2I = 2433024;
static constexpr size_t OFF_WD2H = 2826240;
static constexpr size_t OFF_WMEL = 3219456;    // 400x256 -> 204800
static constexpr size_t OFF_WM   = 3424256;    // 256x256 -> 131072
static constexpr size_t OFF_TPM  = 3555328;    // tanh(pm) f16 [128][128][512] -> 33554432
static constexpr size_t OFF_ENCH = 37109760;   // enc f16 [128][512][128] -> 33554432

// ---------------- prep kernels ----------------
__global__ void pack_w(const float* __restrict__ src, uint4* __restrict__ dst, int N, int K8){
  int idx = blockIdx.x*blockDim.x + threadIdx.x;
  if (idx >= N*K8) return;
  int n = idx % N, k8 = idx / N;
  const float* s = src + (size_t)n*(K8*8) + k8*8;
  dst[idx] = make_uint4(pkh2(s[0],s[1]), pkh2(s[2],s[3]), pkh2(s[4],s[5]), pkh2(s[6],s[7]));
}

__global__ void conv_enc(const float* __restrict__ enc, unsigned* __restrict__ encH){
  size_t i = blockIdx.x*(size_t)blockDim.x + threadIdx.x;
  if (i >= (size_t)128*512*128) return;
  const float2 f = *(const float2*)(enc + 2*i);
  encH[i] = pkh2(f.x, f.y);
}

__global__ __launch_bounds__(1024) void pm_kernel(const float* __restrict__ enc,
    const uint4* __restrict__ Wmp, unsigned* __restrict__ tpm)
{
  int b = blockIdx.y, tc = blockIdx.x;
  int tid = threadIdx.x;
  __shared__ __align__(16) unsigned s_e[4][128];
  if (tid < 512){
    int r = tid >> 7, d2 = tid & 127;
    const float2 f = *(const float2*)(enc + ((size_t)b*512 + tc*4 + r)*256 + 2*d2);
    s_e[r][d2] = pkh2(f.x, f.y);
  }
  __syncthreads();
  int d = tid & 255, r = tid >> 8;
  float acc = mv<256,32>(Wmp, (const uint4*)s_e[r], d);
  float tq = tanhf2(acc);
  float hi = __shfl_down(tq, 1);
  if ((d & 1) == 0)
    tpm[(size_t)b*65536 + (size_t)(d>>1)*512 + (tc*4 + r)] = pkh2(tq, hi);
}

// ---------------- decoder ----------------
__global__ __launch_bounds__(1024) void decoder(
   const float* __restrict__ inputs,
   const float* __restrict__ b1, const float* __restrict__ b2,
   const float* __restrict__ biha, const float* __restrict__ bhha,
   const float* __restrict__ vvec, const float* __restrict__ bp,
   const float* __restrict__ bd1i, const float* __restrict__ bd1h,
   const float* __restrict__ bd2i, const float* __restrict__ bd2h,
   const float* __restrict__ bmel,
   const uint4* __restrict__ W1p, const uint4* __restrict__ W2p,
   const uint4* __restrict__ Wihap, const uint4* __restrict__ Whhap,
   const uint4* __restrict__ Wqp, const uint4* __restrict__ Wpp,
   const uint4* __restrict__ Wd1ip, const uint4* __restrict__ Wd1hp,
   const uint4* __restrict__ Wd2ip, const uint4* __restrict__ Wd2hp,
   const uint4* __restrict__ Wmelp,
   const unsigned* __restrict__ tpm, const unsigned* __restrict__ encH,
   float* __restrict__ out)
{
  const int tid = threadIdx.x;
  const int b = blockIdx.x;

  __shared__ __align__(16) unsigned s_x2[200];   // prenet input packed (frame t-1)
  __shared__ __align__(16) unsigned s_p1[128];   // prenet hidden1 packed
  __shared__ __align__(16) unsigned s_cin2[192]; // [prenet2(64) | ctx(128)]
  __shared__ __align__(16) unsigned s_cat2[256]; // [attn_h(128) | ctx(128)]
  __shared__ __align__(16) unsigned s_di2[128];  // dec_in packed
  __shared__ __align__(16) unsigned s_h12[128];
  __shared__ __align__(16) unsigned s_h22[128];
  __shared__ float  s_gha[768], s_gh1[768], s_gh2[768];  // Whh@h+bhh (early-computed)
  __shared__ float  s_g[768];       // gi: r/z combined-sigm [0..511], gi_n [512..767]
  __shared__ float  s_ahf[256];     // attn_h fp32 master
  __shared__ float  s_h1f[256], s_h2f[256];
  __shared__ float  s_dif[256];     // dec_in fp32 (residual chain)
  __shared__ float4 s_tv[128];      // {tanh(q)2d2, tanh(q)2d2+1, v2d2, v2d2+1}
  __shared__ float  s_lp[2][512];
  __shared__ float2 s_cp[8][128];
  __shared__ float  s_mvp[4][256];
  __shared__ float  s_align[512];
  __shared__ float  s_red[32];

  if (tid < 200) s_x2[tid] = 0u;
  if (tid < 192) s_cin2[tid] = 0u;
  if (tid < 256){ s_cat2[tid]=0u; s_ahf[tid]=0.f; s_h1f[tid]=0.f; s_h2f[tid]=0.f; }
  if (tid < 128){ s_h12[tid]=0u; s_h22[tid]=0u;
                  s_tv[tid].z = vvec[2*tid]; s_tv[tid].w = vvec[2*tid+1]; }
  __syncthreads();

  const unsigned* tpmB = tpm  + (size_t)b*65536;
  const unsigned* encB = encH + (size_t)b*65536;
  const float*    inB  = inputs + (size_t)b*80000;
  float* outMel = out + (size_t)b*200*400;
  float* outAl  = out + (size_t)10240000 + (size_t)b*200*512;

  for (int t = 0; t < 200; ++t){
    // ===== P1: gh_a = Whh_a@attn_h + bhh_a  (768)  ||  prenet1 (256)
    if (tid < 768){
      s_gha[tid] = mvc<768,32,8>(Whhap, (const uint4*)s_cat2, tid) + bhha[tid];
    } else {
      int n = tid - 768;
      float a = fmaxf(mvc<256,50,8>(W1p, (const uint4*)s_x2, n) + b1[n], 0.f);
      float aN = __shfl_down(a, 1);
      if (!(n&1)) s_p1[n>>1] = pkh2(a, aN);
    }
    __syncthreads();
    // ===== P2: gh_d1 (768)  ||  prenet2 (128)
    if (tid < 768){
      s_gh1[tid] = mvc<768,32,8>(Wd1hp, (const uint4*)s_h12, tid) + bd1h[tid];
    } else if (tid < 896){
      int n = tid - 768;
      float a = fmaxf(mvc<128,32,8>(W2p, (const uint4*)s_p1, n) + b2[n], 0.f);
      float aN = __shfl_down(a, 1);
      if (!(n&1)) s_cin2[n>>1] = pkh2(a, aN);
    }
    __syncthreads();
    // ===== P3: gi_a = Wih_a@cell_in + bih_a (768, K=384)
    if (tid < 768){
      float gi = mvc<768,48,8>(Wihap, (const uint4*)s_cin2, tid) + biha[tid];
      s_g[tid] = (tid < 512) ? sigm(gi + s_gha[tid]) : gi;
    }
    __syncthreads();
    //      gate micro -> attn_h
    if (tid < 256){
      float rr = s_g[tid], z = s_g[256+tid];
      float nv = tanhf2(s_g[512+tid] + rr*s_gha[512+tid]);
      float h  = nv + z*(s_ahf[tid] - nv);
      s_ahf[tid] = h;
      float hN = __shfl_down(h, 1);
      if (!(tid&1)) s_cat2[tid>>1] = pkh2(h, hN);
    }
    __syncthreads();
    // ===== P4: q = Wq@attn_h, tanh (256)  ||  gh_d2 (768)
    if (tid < 256){
      float q = mvc<256,32,8>(Wqp, (const uint4*)s_cat2, tid);
      ((float*)&s_tv[tid>>1])[tid&1] = tanhf2(q);
    } else {
      int r = tid - 256;
      s_gh2[r] = mvc<768,32,8>(Wd2hp, (const uint4*)s_h22, r) + bd2h[r];
    }
    __syncthreads();
    // ===== P5: logits via tanh-sum identity (1024, nt streaming loads)
    {
      int tt = tid & 511, dh = tid >> 9;
      const unsigned* tp = tpmB + tt + (size_t)dh*64*512;
      float acc = 0.f;
      #pragma unroll 1
      for (int c = 0; c < 64; c += 16){
        unsigned tw[16];
        #pragma unroll
        for (int i = 0; i < 16; ++i) tw[i] = __builtin_nontemporal_load(&tp[(size_t)(c+i)*512]);
        #pragma unroll
        for (int i = 0; i < 16; ++i){
          h2f ta = __builtin_bit_cast(h2f, tw[i]);
          float4 tv = s_tv[dh*64 + c + i];
          float ta0 = (float)ta.x, ta1 = (float)ta.y;
          acc += tv.z*(ta0+tv.x)*frcp(1.f+ta0*tv.x)
               + tv.w*(ta1+tv.y)*frcp(1.f+ta1*tv.y);
        }
      }
      s_lp[dh][tt] = acc;
    }
    __syncthreads();
    //      softmax over 512
    {
      float lg = (tid < 512) ? (s_lp[0][tid] + s_lp[1][tid]) : -1e30f;
      float m = lg;
      #pragma unroll
      for (int off = 32; off >= 1; off >>= 1) m = fmaxf(m, __shfl_xor(m, off));
      if ((tid & 63) == 0) s_red[tid>>6] = m;
      __syncthreads();
      float M = fmaxf(fmaxf(fmaxf(s_red[0],s_red[1]),fmaxf(s_red[2],s_red[3])),
                      fmaxf(fmaxf(s_red[4],s_red[5]),fmaxf(s_red[6],s_red[7])));
      float e = (tid < 512) ? fexp2(LOG2E*(lg - M)) : 0.f;
      float s = e;
      #pragma unroll
      for (int off = 32; off >= 1; off >>= 1) s += __shfl_xor(s, off);
      if ((tid & 63) == 0) s_red[16+(tid>>6)] = s;
      __syncthreads();
      float S = (s_red[16]+s_red[17])+(s_red[18]+s_red[19])
              + (s_red[20]+s_red[21])+(s_red[22]+s_red[23]);
      float a = e * frcp(S);
      if (tid < 512){ s_align[tid] = a; __builtin_nontemporal_store(a, &outAl[(size_t)t*512 + tid]); }
    }
    __syncthreads();
    // ===== P6: ctx partials (1024, nt streaming loads)
    {
      int d2 = tid & 127, tc = tid >> 7;
      const unsigned* eb = encB + d2 + (size_t)tc*64*128;
      float ax = 0.f, ay = 0.f;
      #pragma unroll 1
      for (int c = 0; c < 64; c += 16){
        unsigned ew[16];
        #pragma unroll
        for (int i = 0; i < 16; ++i) ew[i] = __builtin_nontemporal_load(&eb[(size_t)(c+i)*128]);
        #pragma unroll
        for (int i = 0; i < 16; ++i){
          float a = s_align[tc*64 + c + i];
          h2f e2 = __builtin_bit_cast(h2f, ew[i]);
          ax += a*(float)e2.x; ay += a*(float)e2.y;
        }
      }
      s_cp[tc][d2] = make_float2(ax, ay);
    }
    __syncthreads();
    //      ctx reduce + pack
    if (tid < 256){
      const float* cp = (const float*)s_cp;
      float c = 0.f;
      #pragma unroll
      for (int k = 0; k < 8; ++k) c += cp[k*256 + tid];
      float cN = __shfl_down(c, 1);
      if (!(tid&1)){ unsigned pk = pkh2(c, cN); s_cin2[64+(tid>>1)] = pk; s_cat2[128+(tid>>1)] = pk; }
    }
    __syncthreads();
    // ===== P7: dec_in = Wp@cat(attn_h,ctx) + bp  (split-K4, 1024)
    {
      int n = tid & 255, p = tid >> 8;
      const uint4* xs = (const uint4*)s_cat2;
      float a0 = 0.f, a1 = 0.f;
      #pragma unroll 1
      for (int c = 0; c < 16; c += 8){
        uint4 w[8];
        #pragma unroll
        for (int i = 0; i < 8; ++i) w[i] = Wpp[(size_t)(16*p+c+i)*256 + n];
        #pragma unroll
        for (int i = 0; i < 8; ++i) dot8_2(w[i], xs[16*p+c+i], a0, a1);
      }
      s_mvp[p][n] = a0 + a1;
    }
    __syncthreads();
    if (tid < 256){
      float di = s_mvp[0][tid]+s_mvp[1][tid]+s_mvp[2][tid]+s_mvp[3][tid] + bp[tid];
      s_dif[tid] = di;
      float dN = __shfl_down(di, 1);
      if (!(tid&1)) s_di2[tid>>1] = pkh2(di, dN);
    }
    __syncthreads();
    // ===== P8: gi_d1 (768) -> gates -> h1, residual
    if (tid < 768){
      float gi = mvc<768,32,8>(Wd1ip, (const uint4*)s_di2, tid) + bd1i[tid];
      s_g[tid] = (tid < 512) ? sigm(gi + s_gh1[tid]) : gi;
    }
    __syncthreads();
    if (tid < 256){
      float rr = s_g[tid], z = s_g[256+tid];
      float nv = tanhf2(s_g[512+tid] + rr*s_gh1[512+tid]);
      float h  = nv + z*(s_h1f[tid] - nv);
      s_h1f[tid] = h;
      float di = s_dif[tid] + h; s_dif[tid] = di;
      float hN = __shfl_down(h, 1), dN = __shfl_down(di, 1);
      if (!(tid&1)){ s_h12[tid>>1] = pkh2(h, hN); s_di2[tid>>1] = pkh2(di, dN); }
    }
    __syncthreads();
    // ===== P9: gi_d2 (768) -> gates -> h2, residual
    if (tid < 768){
      float gi = mvc<768,32,8>(Wd2ip, (const uint4*)s_di2, tid) + bd2i[tid];
      s_g[tid] = (tid < 512) ? sigm(gi + s_gh2[tid]) : gi;
    }
    __syncthreads();
    if (tid < 256){
      float rr = s_g[tid], z = s_g[256+tid];
      float nv = tanhf2(s_g[512+tid] + rr*s_gh2[512+tid]);
      float h  = nv + z*(s_h2f[tid] - nv);
      s_h2f[tid] = h;
      float di = s_dif[tid] + h; s_dif[tid] = di;
      float hN = __shfl_down(h, 1), dN = __shfl_down(di, 1);
      if (!(tid&1)){ s_h22[tid>>1] = pkh2(h, hN); s_di2[tid>>1] = pkh2(di, dN); }
    }
    __syncthreads();
    // ===== P0: mel out (400)  ||  x-pack for next step (200)
    if (tid < 400){
      float a = mvc<400,32,8>(Wmelp, (const uint4*)s_di2, tid) + bmel[tid];
      __builtin_nontemporal_store(a, &outMel[(size_t)t*400 + tid]);
    } else if (tid >= 512 && tid < 712 && t+1 < 200){
      int j = tid - 512;
      const float2 f = *(const float2*)(inB + (size_t)t*400 + 2*j);
      s_x2[j] = pkh2(f.x, f.y);
    }
    __syncthreads();
  }
}

// ---------------- launch ----------------
extern "C" void kernel_launch(void* const* d_in, const int* in_sizes, int n_in,
                              void* d_out, int out_size, void* d_ws, size_t ws_size,
                              hipStream_t stream){
  (void)in_sizes; (void)n_in; (void)out_size; (void)ws_size;
  const float* enc    = (const float*)d_in[0];
  const float* inputs = (const float*)d_in[1];
  const float* W1 = (const float*)d_in[2];   const float* b1 = (const float*)d_in[3];
  const float* W2 = (const float*)d_in[4];   const float* b2 = (const float*)d_in[5];
  const float* Wiha = (const float*)d_in[6]; const float* Whha = (const float*)d_in[7];
  const float* biha = (const float*)d_in[8]; const float* bhha = (const float*)d_in[9];
  const float* Wq = (const float*)d_in[10];  const float* v  = (const float*)d_in[11];
  const float* Wm = (const float*)d_in[12];
  const float* Wp = (const float*)d_in[13];  const float* bp = (const float*)d_in[14];
  const float* Wd1i = (const float*)d_in[15]; const float* Wd1h = (const float*)d_in[16];
  const float* bd1i = (const float*)d_in[17]; const float* bd1h = (const float*)d_in[18];
  const float* Wd2i = (const float*)d_in[19]; const float* Wd2h = (const float*)d_in[20];
  const float* bd2i = (const float*)d_in[21]; const float* bd2h = (const float*)d_in[22];
  const float* Wmel = (const float*)d_in[23]; const float* bmel = (const float*)d_in[24];

  char* ws = (char*)d_ws;
  uint4* W1p   = (uint4*)(ws + OFF_W1);
  uint4* W2p   = (uint4*)(ws + OFF_W2);
  uint4* Wihap = (uint4*)(ws + OFF_WIHA);
  uint4* Whhap = (uint4*)(ws + OFF_WHHA);
  uint4* Wqp   = (uint4*)(ws + OFF_WQ);
  uint4* Wpp   = (uint4*)(ws + OFF_WP);
  uint4* Wd1ip = (uint4*)(ws + OFF_WD1I);
  uint4* Wd1hp = (uint4*)(ws + OFF_WD1H);
  uint4* Wd2ip = (uint4*)(ws + OFF_WD2I);
  uint4* Wd2hp = (uint4*)(ws + OFF_WD2H);
  uint4* Wmelp = (uint4*)(ws + OFF_WMEL);
  uint4* Wmp   = (uint4*)(ws + OFF_WM);
  unsigned* tpm  = (unsigned*)(ws + OFF_TPM);
  unsigned* encH = (unsigned*)(ws + OFF_ENCH);

  auto P = [&](const float* s, uint4* dst, int N, int K){
    int k8 = K/8, tot = N*k8;
    pack_w<<<(tot+255)/256, 256, 0, stream>>>(s, dst, N, k8);
  };
  P(W1, W1p, 256, 400);   P(W2, W2p, 128, 256);
  P(Wiha, Wihap, 768, 384); P(Whha, Whhap, 768, 256);
  P(Wq, Wqp, 256, 256);   P(Wm, Wmp, 256, 256);
  P(Wp, Wpp, 256, 512);
  P(Wd1i, Wd1ip, 768, 256); P(Wd1h, Wd1hp, 768, 256);
  P(Wd2i, Wd2ip, 768, 256); P(Wd2h, Wd2hp, 768, 256);
  P(Wmel, Wmelp, 400, 256);

  conv_enc<<<32768, 256, 0, stream>>>(enc, encH);
  pm_kernel<<<dim3(128,128), 1024, 0, stream>>>(enc, Wmp, tpm);

  decoder<<<128, 1024, 0, stream>>>(inputs,
      b1, b2, biha, bhha, v, bp, bd1i, bd1h, bd2i, bd2h, bmel,
      W1p, W2p, Wihap, Whhap, Wqp, Wpp, Wd1ip, Wd1hp, Wd2ip, Wd2hp, Wmelp,
      tpm, encH, (float*)d_out);
}